// Round 11
// baseline (214.960 us; speedup 1.0000x reference)
//
#include <hip/hip_runtime.h>
#include <math.h>

// ===== MEASUREMENT BUILD (R11): p2 launched 17x (idempotent) to measure its
// real per-dispatch cost: p2_slot = (T - 26.7)/16. k1 byte-identical to R9.
constexpr int P2_LAUNCHES = 17;

// Problem constants (fixed by the reference)
constexpr int B_    = 8;
constexpr int CIN_  = 128;
constexpr int H_    = 28;
constexpr int W_    = 28;
constexpr int COUT_ = 256;
constexpr int OH_   = 28;
constexpr int OW_   = 28;
constexpr int L_    = OH_ * OW_;     // 784
constexpr int N_    = B_ * L_;       // 6272
constexpr int NCB_  = 64;
constexpr int K_    = 16;
constexpr int SUB_  = 18;            // 2 channels x 9 taps

// ws layout (byte offsets). idx layout [cb][n] (cb-major).
constexpr size_t WS_IDX  = 0;                  // 64*6272 uchar = 401408 B
constexpr size_t WS_LUT8 = 0x100000;           // 262144 uchar = 256 KB
constexpr size_t WS_BF2  = 0x180000;           // 256 f32 (bias + folded consts)

// ---------------------------------------------------------------------------
// K1: fused phase1 + pack (identical to R9).
// ---------------------------------------------------------------------------
__global__ __launch_bounds__(256, 2) void amm_k1(
    const int* __restrict__ x_q, const int* __restrict__ x_z,
    const int* __restrict__ c_q, const float* __restrict__ c_s,
    const int* __restrict__ c_z, const float* __restrict__ x_s,
    const int* __restrict__ lut_q, const float* __restrict__ lut_s,
    const int* __restrict__ lut_z,
    const int* __restrict__ bias_q, const float* __restrict__ bias_s,
    const int* __restrict__ bias_z,
    unsigned char* __restrict__ idx8, unsigned char* __restrict__ lut8,
    float* __restrict__ biasf2)
{
    const int bx  = blockIdx.x;
    const int tid = threadIdx.x;

    if (bx >= 512) {                       // ---- pack role ----
        const int pb = bx - 512;
        if (pb < 256) {
            const int i = pb * 1024 + tid * 4;       // covers 262144 exactly
            const int4 v = *(const int4*)(lut_q + i);
            uchar4 o;
            o.x = (unsigned char)(v.x + 128);
            o.y = (unsigned char)(v.y + 128);
            o.z = (unsigned char)(v.z + 128);
            o.w = (unsigned char)(v.w + 128);
            *(uchar4*)(lut8 + i) = o;
        } else {
            const double ls = (double)lut_s[0];
            const double c0 = (8192.0 + 64.0 * (double)lut_z[0]) * ls;
            biasf2[tid] = (float)((double)(bias_q[tid] - bias_z[0]) *
                                  (double)bias_s[0] - c0);
        }
        return;
    }

    // ---- argmin role ----
    const int cb = bx & 63;
    const int b  = bx >> 6;

    __shared__ float sx[2][900];     // 30x30 zero-padded, 7.2 KB
    __shared__ float c_lds[288];     // [s][k] k-major, float(c_q - zc)
    __shared__ float y2_lds[16];

    const int zc = c_z[cb];
    for (int i = tid; i < 1800; i += 256) ((float*)sx)[i] = 0.0f;
    for (int i = tid; i < 288; i += 256) {
        const int k = i / SUB_, s = i - k * SUB_;
        c_lds[s * 16 + k] = (float)(c_q[cb * 288 + i] - zc);   // exact int
    }
    __syncthreads();

    const int xz = x_z[0];
    for (int i = tid; i < 2 * 784; i += 256) {
        const int c2 = i >= 784;
        const int r  = i - c2 * 784;
        const int h  = r / 28;
        const int w  = r - h * 28;
        sx[c2][(h + 1) * 30 + (w + 1)] =
            (float)(x_q[(size_t)(b * CIN_ + 2 * cb + c2) * L_ + r] - xz);
    }
    if (tid < 16) {                 // y2 in double, same order as before
        const double csf = (double)c_s[cb];
        const double den = (double)x_s[0] * csf;
        double s2 = 0.0;
        for (int s = 0; s < SUB_; ++s) {
            const double d = (double)c_lds[s * 16 + tid] * csf;
            s2 += d * d;
        }
        y2_lds[tid] = (float)(int)rint(s2 / den);   // < 2^24 -> exact in f32
    }
    __syncthreads();

    if (tid < 196) {
        float tap[4][SUB_];
        int   posr[4];
        #pragma unroll
        for (int ps = 0; ps < 4; ++ps) {
            const int p  = tid + 196 * ps;
            posr[ps] = p;
            const int oh = p / 28;
            const int ow = p - oh * 28;
            const int base = oh * 30 + ow;
            #pragma unroll
            for (int c2 = 0; c2 < 2; ++c2)
                #pragma unroll
                for (int kh = 0; kh < 3; ++kh)
                    #pragma unroll
                    for (int kw = 0; kw < 3; ++kw)
                        tap[ps][c2 * 9 + kh * 3 + kw] =
                            sx[c2][base + kh * 30 + kw];
        }

        float bestd[4] = {3.0e38f, 3.0e38f, 3.0e38f, 3.0e38f};
        int   bestk[4] = {0, 0, 0, 0};

        #pragma unroll
        for (int kc = 0; kc < 4; ++kc) {
            float acc[4][4];
            #pragma unroll
            for (int ps = 0; ps < 4; ++ps)
                #pragma unroll
                for (int kk = 0; kk < 4; ++kk) acc[ps][kk] = 0.0f;

            #pragma unroll
            for (int s = 0; s < SUB_; ++s) {
                const float4 c4 = *(const float4*)&c_lds[s * 16 + kc * 4];
                #pragma unroll
                for (int ps = 0; ps < 4; ++ps) {
                    const float xs = tap[ps][s];
                    acc[ps][0] = fmaf(xs, c4.x, acc[ps][0]);
                    acc[ps][1] = fmaf(xs, c4.y, acc[ps][1]);
                    acc[ps][2] = fmaf(xs, c4.z, acc[ps][2]);
                    acc[ps][3] = fmaf(xs, c4.w, acc[ps][3]);
                }
            }
            #pragma unroll
            for (int kk = 0; kk < 4; ++kk) {
                const float yk = y2_lds[kc * 4 + kk];
                #pragma unroll
                for (int ps = 0; ps < 4; ++ps) {
                    const float d = fmaf(-2.0f, acc[ps][kk], yk);
                    if (d < bestd[ps]) { bestd[ps] = d; bestk[ps] = kc * 4 + kk; }
                }
            }
        }

        unsigned char* op = idx8 + (size_t)cb * N_ + b * L_;
        #pragma unroll
        for (int ps = 0; ps < 4; ++ps)
            op[posr[ps]] = (unsigned char)bestk[ps];
    }
}

// ---------------------------------------------------------------------------
// K2 (identical to R9): per-wave position, biased-uint8 LUT gather,
// packed-u16 carry-free accumulation, LDS transpose, int4 stores.
// ---------------------------------------------------------------------------
__global__ __launch_bounds__(256, 6) void amm_phase2(
    const unsigned char* __restrict__ idx8, const unsigned char* __restrict__ lut8,
    const float* __restrict__ lut_s, const float* __restrict__ biasf2,
    const float* __restrict__ out_s, const int* __restrict__ out_z,
    int* __restrict__ out)
{
    const int tid  = threadIdx.x;
    const int lane = tid & 63;
    const int w    = __builtin_amdgcn_readfirstlane(tid >> 6);
    const int nb   = blockIdx.x * 4;
    const int b    = nb / L_;
    const int r0   = nb - b * L_;
    const int pos  = w;
    const int sh   = 8 * pos;

    __shared__ unsigned int res[4][130];

    unsigned int accLo = 0, accHi = 0;
    #pragma unroll
    for (int bt = 0; bt < 4; ++bt) {
        unsigned int kw[16];
        #pragma unroll
        for (int i = 0; i < 16; ++i) {
            const int cbi = bt * 16 + i;
            kw[i] = *(const unsigned int*)(idx8 + (size_t)cbi * N_ + nb);
        }
        unsigned int t[16];
        #pragma unroll
        for (int i = 0; i < 16; ++i) {
            const unsigned int k = (kw[i] >> sh) & 0xffu;
            const int cbi = bt * 16 + i;
            t[i] = *(const unsigned int*)(lut8 +
                    ((size_t)((cbi << 4) + k) << 8) + (lane << 2));
        }
        #pragma unroll
        for (int i = 0; i < 16; ++i) {
            accLo += t[i] & 0x00FF00FFu;
            accHi += (t[i] >> 8) & 0x00FF00FFu;
        }
    }

    res[pos][lane * 2]     = accLo;
    res[pos][lane * 2 + 1] = accHi;
    __syncthreads();

    const float lsf = lut_s[0];
    const float osf = out_s[0];
    const float ozf = (float)out_z[0];

    const int co   = tid;
    const int c    = co & 3;
    const int u    = (co >> 2) * 2 + (c & 1);
    const int half = c >> 1;
    const float bf = biasf2[co];

    int4 ov;
    int* ovp = (int*)&ov;
    #pragma unroll
    for (int p = 0; p < 4; ++p) {
        const unsigned int vv = res[p][u];
        const int sv = (int)((vv >> (16 * half)) & 0xffffu);
        float f = (float)sv * lsf + bf;
        f = fmaxf(f, 0.0f) / osf + ozf;
        f = fminf(fmaxf(f, -128.0f), 127.0f);
        ovp[p] = (int)rintf(f);
    }
    *(int4*)(out + (size_t)(b * COUT_ + co) * L_ + r0) = ov;
}

extern "C" void kernel_launch(void* const* d_in, const int* in_sizes, int n_in,
                              void* d_out, int out_size, void* d_ws, size_t ws_size,
                              hipStream_t stream)
{
    const int*   x_q    = (const int*)  d_in[0];
    const float* x_s    = (const float*)d_in[1];
    const int*   x_z    = (const int*)  d_in[2];
    const int*   c_q    = (const int*)  d_in[3];
    const float* c_s    = (const float*)d_in[4];
    const int*   c_z    = (const int*)  d_in[5];
    const int*   lut_q  = (const int*)  d_in[6];
    const float* lut_s  = (const float*)d_in[7];
    const int*   lut_z  = (const int*)  d_in[8];
    const int*   bias_q = (const int*)  d_in[9];
    const float* bias_s = (const float*)d_in[10];
    const int*   bias_z = (const int*)  d_in[11];
    const float* out_s  = (const float*)d_in[12];
    const int*   out_z  = (const int*)  d_in[13];

    char* ws = (char*)d_ws;
    unsigned char* idx8 = (unsigned char*)(ws + WS_IDX);
    unsigned char* lut8 = (unsigned char*)(ws + WS_LUT8);
    float* biasf2 = (float*)(ws + WS_BF2);

    amm_k1<<<dim3(769), 256, 0, stream>>>(x_q, x_z, c_q, c_s, c_z, x_s,
                                          lut_q, lut_s, lut_z,
                                          bias_q, bias_s, bias_z,
                                          idx8, lut8, biasf2);

    // p2 is idempotent: 17 serialized launches measure its real
    // per-dispatch cost via dur_us: p2_slot = (T - 26.7)/16.
    for (int it = 0; it < P2_LAUNCHES; ++it)
        amm_phase2<<<dim3(N_ / 4), 256, 0, stream>>>(
            idx8, lut8, lut_s, biasf2, out_s, out_z, (int*)d_out);
}

// Round 12
// 53.659 us; speedup vs baseline: 4.0060x; 4.0060x over previous
//
#include <hip/hip_runtime.h>
#include <math.h>

// Problem constants (fixed by the reference)
constexpr int CIN_  = 128;
constexpr int COUT_ = 256;
constexpr int L_    = 784;
constexpr int N_    = 6272;
constexpr int NCB_  = 64;
constexpr int K_    = 16;
constexpr int SUB_  = 18;
constexpr int NGRP  = N_ / 4;    // 1568 groups of 4 consecutive positions
constexpr int NBLK  = 512;       // grid of fused kernel (= 2 blocks/CU)

constexpr size_t WS_LUT8 = 0;    // 262144 uchar = 256 KB

// ---------------------------------------------------------------------------
// Pack: lut int32 -> biased uint8 (v+128). 256 blocks x 256 thr x 1 int4.
// ---------------------------------------------------------------------------
__global__ __launch_bounds__(256) void amm_pack(
    const int* __restrict__ lut_q, unsigned char* __restrict__ lut8)
{
    const int i = (blockIdx.x * 256 + threadIdx.x) * 4;
    const int4 v = *(const int4*)(lut_q + i);
    uchar4 o;
    o.x = (unsigned char)(v.x + 128);
    o.y = (unsigned char)(v.y + 128);
    o.z = (unsigned char)(v.z + 128);
    o.w = (unsigned char)(v.w + 128);
    *(uchar4*)(lut8 + i) = o;
}

// ---------------------------------------------------------------------------
// Fused argmin + gather. Block owns groups g = bid, bid+512, ... (4 positions
// each, same b and same output row). Per block init: centroids as bf16 pairs
// (exact: |c_q-zc| <= 132 < 256) + y2 (double, same order -> bit-identical)
// + dequant bias, all in LDS. Per group: stage x-tile (128ch x 3x6, f32,
// XOR-swizzled), thread (cb,kq) computes 4 k x 4 pos dots, 2-round shfl_xor
// lexicographic argmin (first-min tie-break), idx -> LDS, then the proven
// uint8-LUT gather + packed-u16 accumulation + LDS transpose epilogue.
// ---------------------------------------------------------------------------
__global__ __launch_bounds__(256, 2) void amm_fused(
    const int* __restrict__ x_q, const int* __restrict__ x_z,
    const int* __restrict__ c_q, const float* __restrict__ c_s,
    const int* __restrict__ c_z, const float* __restrict__ x_s,
    const unsigned char* __restrict__ lut8,
    const float* __restrict__ lut_s, const int* __restrict__ lut_z,
    const int* __restrict__ bias_q, const float* __restrict__ bias_s,
    const int* __restrict__ bias_z,
    const float* __restrict__ out_s, const int* __restrict__ out_z,
    int* __restrict__ out)
{
    // [cb][k][12 dwords]: d0..8 = 18 bf16 (s pairs), d9 = y2 (f32 bits)
    __shared__ __align__(16) unsigned int c_dw[NCB_ * 192];   // 49152 B
    __shared__ __align__(16) float xt[2 * 64 * 24];           // 12288 B
    __shared__ unsigned int sidx[4][16];                      // idx bytes [pos][cb/4]
    __shared__ unsigned int res[4][130];                      // 2080 B
    __shared__ float bias_l[256];                             // 1024 B
    __shared__ int czl[64];                                   // 256 B

    const int tid = threadIdx.x;
    const int bid = blockIdx.x;

    // ---- block init ----
    if (tid < 64) czl[tid] = c_z[tid];
    {
        const double ls = (double)lut_s[0];
        const double c0 = (8192.0 + 64.0 * (double)lut_z[0]) * ls;
        bias_l[tid] = (float)((double)(bias_q[tid] - bias_z[0]) *
                              (double)bias_s[0] - c0);
    }
    __syncthreads();

    // centroids -> bf16 pairs (exact), one dword per thread-element
    for (int e = tid; e < NCB_ * K_ * 9; e += 256) {          // 9216 dwords
        const int cb = e / 144, rem = e - cb * 144;
        const int k = rem / 9, d = rem - k * 9;
        const int base = cb * 288 + k * 18 + d * 2;
        const int zc = czl[cb];
        const float f0 = (float)(c_q[base] - zc);
        const float f1 = (float)(c_q[base + 1] - zc);
        const unsigned int pk = (__float_as_uint(f0) >> 16) |
                                (__float_as_uint(f1) & 0xFFFF0000u);
        c_dw[(cb * 192 + k * 12 + d) ^ ((cb & 7) << 2)] = pk;
    }
    __syncthreads();

    // y2 (double, s ascending -> bit-identical to prior rounds) into slot 9
    {
        const double xsf = (double)x_s[0];
        for (int j = tid; j < NCB_ * K_; j += 256) {
            const int cb = j >> 4, k = j & 15;
            const double csf = (double)c_s[cb];
            const double den = xsf * csf;
            const int kb = cb * 192 + k * 12;
            const int xw = (cb & 7) << 2;
            double s2 = 0.0;
            #pragma unroll
            for (int d = 0; d < 9; ++d) {
                const unsigned int pk = c_dw[(kb + d) ^ xw];
                const double a0 = (double)__uint_as_float(pk << 16) * csf;
                const double a1 = (double)__uint_as_float(pk & 0xFFFF0000u) * csf;
                s2 += a0 * a0;
                s2 += a1 * a1;
            }
            c_dw[(kb + 9) ^ xw] = __float_as_uint((float)(int)rint(s2 / den));
        }
    }

    const int xz   = x_z[0];
    const int lane = tid & 63;
    const int pos  = __builtin_amdgcn_readfirstlane(tid >> 6);
    const int cb   = tid >> 2;
    const int kq   = tid & 3;
    const int xwc  = (cb & 7) << 2;

    for (int g = bid; g < NGRP; g += NBLK) {
        const int n0  = g * 4;
        const int b   = n0 / L_;
        const int r0  = n0 - b * L_;
        const int oh  = r0 / 28;
        const int ow0 = r0 - oh * 28;

        __syncthreads();   // protect xt/sidx/res from previous iteration
        // stage x tile: 128 ch x 3 rows x 6 cols, zero-padded, XOR-swizzled
        for (int e = tid; e < CIN_ * 18; e += 256) {
            const int ch = e / 18, rem = e - ch * 18;
            const int rr = rem / 6, cc = rem - rr * 6;
            const int h = oh - 1 + rr, w = ow0 - 1 + cc;
            float v = 0.0f;
            if ((unsigned)h < 28u && (unsigned)w < 28u)
                v = (float)(x_q[((b * CIN_ + ch) * 28 + h) * 28 + w] - xz);
            const int ch2 = ch & 1, cbch = ch >> 1;
            xt[(((ch2 * 64 + cbch) * 24) + rr * 8 + cc) ^ ((cbch & 7) << 2)] = v;
        }
        __syncthreads();

        // ---- argmin ----
        float xr[2][3][6];
        #pragma unroll
        for (int ch2 = 0; ch2 < 2; ++ch2)
            #pragma unroll
            for (int rr = 0; rr < 3; ++rr) {
                const int lb = (ch2 * 64 + cb) * 24 + rr * 8;
                const float4 a  = *(const float4*)&xt[lb ^ xwc];
                const float2 b2 = *(const float2*)&xt[(lb + 4) ^ xwc];
                xr[ch2][rr][0] = a.x;  xr[ch2][rr][1] = a.y;
                xr[ch2][rr][2] = a.z;  xr[ch2][rr][3] = a.w;
                xr[ch2][rr][4] = b2.x; xr[ch2][rr][5] = b2.y;
            }

        float bd[4] = {3.0e38f, 3.0e38f, 3.0e38f, 3.0e38f};
        int   bk[4] = {0, 0, 0, 0};
        #pragma unroll
        for (int j = 0; j < 4; ++j) {
            const int k  = kq * 4 + j;
            const int kb = cb * 192 + k * 12;
            const uint4 A  = *(const uint4*)&c_dw[kb ^ xwc];
            const uint4 Bv = *(const uint4*)&c_dw[(kb + 4) ^ xwc];
            const unsigned int C8 = c_dw[(kb + 8) ^ xwc];
            const float yk = __uint_as_float(c_dw[(kb + 9) ^ xwc]);
            const unsigned int wsv[9] = {A.x, A.y, A.z, A.w,
                                         Bv.x, Bv.y, Bv.z, Bv.w, C8};
            float ck[18];
            #pragma unroll
            for (int d2 = 0; d2 < 9; ++d2) {
                ck[2 * d2]     = __uint_as_float(wsv[d2] << 16);
                ck[2 * d2 + 1] = __uint_as_float(wsv[d2] & 0xFFFF0000u);
            }
            #pragma unroll
            for (int p = 0; p < 4; ++p) {
                float acc = 0.0f;
                #pragma unroll
                for (int s = 0; s < 18; ++s) {
                    const int ch2 = (s >= 9) ? 1 : 0;
                    const int r9  = s - ch2 * 9;
                    const int rr  = r9 / 3, scc = r9 - rr * 3;
                    acc = fmaf(xr[ch2][rr][scc + p], ck[s], acc);
                }
                const float dd = fmaf(-2.0f, acc, yk);   // exact integer-valued
                if (dd < bd[p]) { bd[p] = dd; bk[p] = k; }  // in-thread first-min
            }
        }
        // cross-thread (4 kq lanes per cb) lexicographic (d, k) min
        #pragma unroll
        for (int p = 0; p < 4; ++p) {
            #pragma unroll
            for (int m = 1; m < 4; m <<= 1) {
                const float od = __shfl_xor(bd[p], m, 64);
                const int   ok = __shfl_xor(bk[p], m, 64);
                if (od < bd[p] || (od == bd[p] && ok < bk[p])) {
                    bd[p] = od; bk[p] = ok;
                }
            }
            if (kq == 0)
                ((unsigned char*)&sidx[p][0])[cb] = (unsigned char)bk[p];
        }
        __syncthreads();

        // ---- gather (wave = one position) ----
        unsigned int accLo = 0, accHi = 0;
        {
            const unsigned int* ip = &sidx[pos][0];
            #pragma unroll
            for (int qt = 0; qt < 4; ++qt) {
                unsigned int dw[4];
                #pragma unroll
                for (int jj = 0; jj < 4; ++jj) dw[jj] = ip[qt * 4 + jj];
                unsigned int t[16];
                #pragma unroll
                for (int i = 0; i < 16; ++i) {
                    const int cbi = qt * 16 + i;
                    const unsigned int k = (dw[i >> 2] >> (8 * (i & 3))) & 0xffu;
                    t[i] = *(const unsigned int*)(lut8 +
                            ((size_t)((cbi << 4) + k) << 8) + (lane << 2));
                }
                #pragma unroll
                for (int i = 0; i < 16; ++i) {
                    accLo += t[i] & 0x00FF00FFu;
                    accHi += (t[i] >> 8) & 0x00FF00FFu;
                }
            }
        }
        res[pos][lane * 2]     = accLo;
        res[pos][lane * 2 + 1] = accHi;
        __syncthreads();

        // ---- epilogue ----
        const float lsf = lut_s[0];
        const float osf = out_s[0];
        const float ozf = (float)out_z[0];
        const int co    = tid;
        const int cpart = co & 3;
        const int u     = (co >> 2) * 2 + (cpart & 1);
        const int half  = cpart >> 1;
        const float bf  = bias_l[co];
        int4 ov; int* ovp = (int*)&ov;
        #pragma unroll
        for (int p = 0; p < 4; ++p) {
            const unsigned int vv = res[p][u];
            const int sv = (int)((vv >> (16 * half)) & 0xffffu);
            float f = (float)sv * lsf + bf;
            f = fmaxf(f, 0.0f) / osf + ozf;
            f = fminf(fmaxf(f, -128.0f), 127.0f);
            ovp[p] = (int)rintf(f);
        }
        *(int4*)(out + (size_t)(b * COUT_ + co) * L_ + r0) = ov;
    }
}

extern "C" void kernel_launch(void* const* d_in, const int* in_sizes, int n_in,
                              void* d_out, int out_size, void* d_ws, size_t ws_size,
                              hipStream_t stream)
{
    const int*   x_q    = (const int*)  d_in[0];
    const float* x_s    = (const float*)d_in[1];
    const int*   x_z    = (const int*)  d_in[2];
    const int*   c_q    = (const int*)  d_in[3];
    const float* c_s    = (const float*)d_in[4];
    const int*   c_z    = (const int*)  d_in[5];
    const int*   lut_q  = (const int*)  d_in[6];
    const float* lut_s  = (const float*)d_in[7];
    const int*   lut_z  = (const int*)  d_in[8];
    const int*   bias_q = (const int*)  d_in[9];
    const float* bias_s = (const float*)d_in[10];
    const int*   bias_z = (const int*)  d_in[11];
    const float* out_s  = (const float*)d_in[12];
    const int*   out_z  = (const int*)  d_in[13];

    unsigned char* lut8 = (unsigned char*)((char*)d_ws + WS_LUT8);

    amm_pack<<<dim3(256), 256, 0, stream>>>(lut_q, lut8);

    amm_fused<<<dim3(NBLK), 256, 0, stream>>>(
        x_q, x_z, c_q, c_s, c_z, x_s, lut8, lut_s, lut_z,
        bias_q, bias_s, bias_z, out_s, out_z, (int*)d_out);
}

// Round 13
// 24.664 us; speedup vs baseline: 8.7154x; 2.1756x over previous
//
#include <hip/hip_runtime.h>
#include <math.h>

// Problem constants (fixed by the reference)
constexpr int B_    = 8;
constexpr int CIN_  = 128;
constexpr int H_    = 28;
constexpr int W_    = 28;
constexpr int COUT_ = 256;
constexpr int OH_   = 28;
constexpr int OW_   = 28;
constexpr int L_    = OH_ * OW_;     // 784
constexpr int N_    = B_ * L_;       // 6272
constexpr int NCB_  = 64;
constexpr int K_    = 16;
constexpr int SUB_  = 18;            // 2 channels x 9 taps

// ws layout (byte offsets). idx layout [cb][n] (cb-major).
constexpr size_t WS_IDX  = 0;                  // 64*6272 uchar = 401408 B
constexpr size_t WS_LUT8 = 0x100000;           // 262144 uchar = 256 KB
constexpr size_t WS_BF2  = 0x180000;           // 256 f32 (bias + folded consts)

// ---------------------------------------------------------------------------
// K1: fused phase1 + pack (byte-identical to R9).
// ---------------------------------------------------------------------------
__global__ __launch_bounds__(256, 2) void amm_k1(
    const int* __restrict__ x_q, const int* __restrict__ x_z,
    const int* __restrict__ c_q, const float* __restrict__ c_s,
    const int* __restrict__ c_z, const float* __restrict__ x_s,
    const int* __restrict__ lut_q, const float* __restrict__ lut_s,
    const int* __restrict__ lut_z,
    const int* __restrict__ bias_q, const float* __restrict__ bias_s,
    const int* __restrict__ bias_z,
    unsigned char* __restrict__ idx8, unsigned char* __restrict__ lut8,
    float* __restrict__ biasf2)
{
    const int bx  = blockIdx.x;
    const int tid = threadIdx.x;

    if (bx >= 512) {                       // ---- pack role ----
        const int pb = bx - 512;
        if (pb < 256) {
            const int i = pb * 1024 + tid * 4;       // covers 262144 exactly
            const int4 v = *(const int4*)(lut_q + i);
            uchar4 o;
            o.x = (unsigned char)(v.x + 128);
            o.y = (unsigned char)(v.y + 128);
            o.z = (unsigned char)(v.z + 128);
            o.w = (unsigned char)(v.w + 128);
            *(uchar4*)(lut8 + i) = o;
        } else {
            const double ls = (double)lut_s[0];
            const double c0 = (8192.0 + 64.0 * (double)lut_z[0]) * ls;
            biasf2[tid] = (float)((double)(bias_q[tid] - bias_z[0]) *
                                  (double)bias_s[0] - c0);
        }
        return;
    }

    // ---- argmin role ----
    const int cb = bx & 63;
    const int b  = bx >> 6;

    __shared__ float sx[2][900];     // 30x30 zero-padded, 7.2 KB
    __shared__ float c_lds[288];     // [s][k] k-major, float(c_q - zc)
    __shared__ float y2_lds[16];

    const int zc = c_z[cb];
    for (int i = tid; i < 1800; i += 256) ((float*)sx)[i] = 0.0f;
    for (int i = tid; i < 288; i += 256) {
        const int k = i / SUB_, s = i - k * SUB_;
        c_lds[s * 16 + k] = (float)(c_q[cb * 288 + i] - zc);   // exact int
    }
    __syncthreads();

    const int xz = x_z[0];
    for (int i = tid; i < 2 * 784; i += 256) {
        const int c2 = i >= 784;
        const int r  = i - c2 * 784;
        const int h  = r / 28;
        const int w  = r - h * 28;
        sx[c2][(h + 1) * 30 + (w + 1)] =
            (float)(x_q[(size_t)(b * CIN_ + 2 * cb + c2) * L_ + r] - xz);
    }
    if (tid < 16) {                 // y2 in double, same order as before
        const double csf = (double)c_s[cb];
        const double den = (double)x_s[0] * csf;
        double s2 = 0.0;
        for (int s = 0; s < SUB_; ++s) {
            const double d = (double)c_lds[s * 16 + tid] * csf;
            s2 += d * d;
        }
        y2_lds[tid] = (float)(int)rint(s2 / den);   // < 2^24 -> exact in f32
    }
    __syncthreads();

    if (tid < 196) {
        float tap[4][SUB_];
        int   posr[4];
        #pragma unroll
        for (int ps = 0; ps < 4; ++ps) {
            const int p  = tid + 196 * ps;
            posr[ps] = p;
            const int oh = p / 28;
            const int ow = p - oh * 28;
            const int base = oh * 30 + ow;
            #pragma unroll
            for (int c2 = 0; c2 < 2; ++c2)
                #pragma unroll
                for (int kh = 0; kh < 3; ++kh)
                    #pragma unroll
                    for (int kw = 0; kw < 3; ++kw)
                        tap[ps][c2 * 9 + kh * 3 + kw] =
                            sx[c2][base + kh * 30 + kw];
        }

        float bestd[4] = {3.0e38f, 3.0e38f, 3.0e38f, 3.0e38f};
        int   bestk[4] = {0, 0, 0, 0};

        #pragma unroll
        for (int kc = 0; kc < 4; ++kc) {
            float acc[4][4];
            #pragma unroll
            for (int ps = 0; ps < 4; ++ps)
                #pragma unroll
                for (int kk = 0; kk < 4; ++kk) acc[ps][kk] = 0.0f;

            #pragma unroll
            for (int s = 0; s < SUB_; ++s) {
                const float4 c4 = *(const float4*)&c_lds[s * 16 + kc * 4];
                #pragma unroll
                for (int ps = 0; ps < 4; ++ps) {
                    const float xs = tap[ps][s];
                    acc[ps][0] = fmaf(xs, c4.x, acc[ps][0]);
                    acc[ps][1] = fmaf(xs, c4.y, acc[ps][1]);
                    acc[ps][2] = fmaf(xs, c4.z, acc[ps][2]);
                    acc[ps][3] = fmaf(xs, c4.w, acc[ps][3]);
                }
            }
            #pragma unroll
            for (int kk = 0; kk < 4; ++kk) {
                const float yk = y2_lds[kc * 4 + kk];
                #pragma unroll
                for (int ps = 0; ps < 4; ++ps) {
                    const float d = fmaf(-2.0f, acc[ps][kk], yk);
                    if (d < bestd[ps]) { bestd[ps] = d; bestk[ps] = kc * 4 + kk; }
                }
            }
        }

        unsigned char* op = idx8 + (size_t)cb * N_ + b * L_;
        #pragma unroll
        for (int ps = 0; ps < 4; ++ps)
            op[posr[ps]] = (unsigned char)bestk[ps];
    }
}

// ---------------------------------------------------------------------------
// K2 v3: grid 1568 x 256; wave = one position. dwordx4 gather: per round t,
// lane L loads 16B of LUT row cb = 4t + (L>>4) at byte (L&15)*16 -> 16 VMEM
// loads/wave (was 64+16). 8 packed-u16 accumulators per lane (16 couts);
// shfl_xor(16,32) butterfly merges the 4 row classes (sums <= 16320, carry-
// free). idx staged once to LDS (64 dwords, broadcast reads). Epilogue:
// LDS transpose with the new word permutation; int4 stores (4 consecutive r).
// ---------------------------------------------------------------------------
__global__ __launch_bounds__(256, 6) void amm_phase2(
    const unsigned char* __restrict__ idx8, const unsigned char* __restrict__ lut8,
    const float* __restrict__ lut_s, const float* __restrict__ biasf2,
    const float* __restrict__ out_s, const int* __restrict__ out_z,
    int* __restrict__ out)
{
    const int tid  = threadIdx.x;
    const int lane = tid & 63;
    const int wv   = __builtin_amdgcn_readfirstlane(tid >> 6);  // position
    const int nb   = blockIdx.x * 4;
    const int b    = nb / L_;          // uniform; 784%4==0 so no b crossing
    const int r0   = nb - b * L_;
    const int sh   = 8 * wv;

    __shared__ unsigned int sidx[64];      // [cb]: 4 pos bytes
    __shared__ unsigned int res[4][132];   // [pos][128 words = 256 couts] +pad

    if (tid < 64)
        sidx[tid] = *(const unsigned int*)(idx8 + (size_t)tid * N_ + nb);
    __syncthreads();

    const int cbq = lane >> 4;         // row class 0..3
    const int coq = lane & 15;         // 16B cout-quad within the row

    unsigned int acc[8] = {0, 0, 0, 0, 0, 0, 0, 0};
    #pragma unroll
    for (int tb = 0; tb < 4; ++tb) {   // 4 batches of 4 rounds (ILP)
        uint4 v[4];
        #pragma unroll
        for (int j = 0; j < 4; ++j) {
            const int cb = (tb * 4 + j) * 4 + cbq;
            const unsigned int k = (sidx[cb] >> sh) & 0xffu;
            v[j] = *(const uint4*)(lut8 + ((size_t)((cb << 4) + k) << 8)
                                        + (coq << 4));
        }
        #pragma unroll
        for (int j = 0; j < 4; ++j) {
            const unsigned int d[4] = {v[j].x, v[j].y, v[j].z, v[j].w};
            #pragma unroll
            for (int q = 0; q < 4; ++q) {
                acc[2 * q]     += d[q] & 0x00FF00FFu;
                acc[2 * q + 1] += (d[q] >> 8) & 0x00FF00FFu;
            }
        }
    }

    // merge the 4 row classes (u16 halves never overflow: <= 16320)
    #pragma unroll
    for (int j = 0; j < 8; ++j) {
        acc[j] += __shfl_xor(acc[j], 16, 64);
        acc[j] += __shfl_xor(acc[j], 32, 64);
    }
    if (cbq == 0) {
        #pragma unroll
        for (int j = 0; j < 8; ++j) res[wv][coq * 8 + j] = acc[j];
    }
    __syncthreads();

    // ---- epilogue: thread t owns cout = t; int4 store of 4 consecutive r ----
    const float lsf = lut_s[0];
    const float osf = out_s[0];
    const float ozf = (float)out_z[0];

    const int co   = tid;
    // word = span*8 + 2*d + (co&1), half = (co>>1)&1
    const int u    = (co >> 4) * 8 + ((co & 15) >> 2) * 2 + (co & 1);
    const int half = (co >> 1) & 1;
    const float bf = biasf2[co];

    int4 ov;
    int* ovp = (int*)&ov;
    #pragma unroll
    for (int p = 0; p < 4; ++p) {
        const unsigned int vv = res[p][u];
        const int sv = (int)((vv >> (16 * half)) & 0xffffu);
        float f = (float)sv * lsf + bf;
        f = fmaxf(f, 0.0f) / osf + ozf;
        f = fminf(fmaxf(f, -128.0f), 127.0f);
        ovp[p] = (int)rintf(f);
    }
    *(int4*)(out + (size_t)(b * COUT_ + co) * L_ + r0) = ov;
}

extern "C" void kernel_launch(void* const* d_in, const int* in_sizes, int n_in,
                              void* d_out, int out_size, void* d_ws, size_t ws_size,
                              hipStream_t stream)
{
    const int*   x_q    = (const int*)  d_in[0];
    const float* x_s    = (const float*)d_in[1];
    const int*   x_z    = (const int*)  d_in[2];
    const int*   c_q    = (const int*)  d_in[3];
    const float* c_s    = (const float*)d_in[4];
    const int*   c_z    = (const int*)  d_in[5];
    const int*   lut_q  = (const int*)  d_in[6];
    const float* lut_s  = (const float*)d_in[7];
    const int*   lut_z  = (const int*)  d_in[8];
    const int*   bias_q = (const int*)  d_in[9];
    const float* bias_s = (const float*)d_in[10];
    const int*   bias_z = (const int*)  d_in[11];
    const float* out_s  = (const float*)d_in[12];
    const int*   out_z  = (const int*)  d_in[13];

    char* ws = (char*)d_ws;
    unsigned char* idx8 = (unsigned char*)(ws + WS_IDX);
    unsigned char* lut8 = (unsigned char*)(ws + WS_LUT8);
    float* biasf2 = (float*)(ws + WS_BF2);

    amm_k1<<<dim3(769), 256, 0, stream>>>(x_q, x_z, c_q, c_s, c_z, x_s,
                                          lut_q, lut_s, lut_z,
                                          bias_q, bias_s, bias_z,
                                          idx8, lut8, biasf2);

    amm_phase2<<<dim3(N_ / 4), 256, 0, stream>>>(
        idx8, lut8, lut_s, biasf2, out_s, out_z, (int*)d_out);
}